// Round 17
// baseline (258.606 us; speedup 1.0000x reference)
//
#include <hip/hip_runtime.h>
#include <hip/hip_fp16.h>
#include <math.h>

#define NN 100000
#define NE 3200000
#define FIN 64
#define HID 20
#define NG 128
#define NC 10
#define ROWD 12               // padded row: 12 dwords = 24 halfs = 48 B

// ---- two-level counting-sort params ----
#define BSH 8                 // nodes per bucket = 256
#define NB1 391               // ceil(NN / 256)
#define NB1P 392
#define NBLK1 256             // partition blocks: covers all 256 CUs
#define BLK1T 1024            // threads per partition block
#define E1 (NE / NBLK1)       // 12500 exactly
#define NXCD 8
#define P2CAP 6144            // half-bucket stage capacity

typedef float floatx4 __attribute__((ext_vector_type(4)));

__device__ __forceinline__ int swz_blk(int bid) {
    return (bid & (NXCD - 1)) * (NBLK1 / NXCD) + (bid >> 3);
}

// ---------------- t0 = x @ W1a, stored f16 padded rows ----------------
__global__ __launch_bounds__(256) void k_in_gemm_h(const float* __restrict__ x,
                                                   const float* __restrict__ W,
                                                   __half* __restrict__ t) {
    __shared__ float sW[FIN * HID];
    for (int i = threadIdx.x; i < FIN * HID; i += blockDim.x) sW[i] = W[i];
    __syncthreads();
    int node = blockIdx.x * blockDim.x + threadIdx.x;
    if (node >= NN) return;
    float acc[HID];
#pragma unroll
    for (int f = 0; f < HID; ++f) acc[f] = 0.f;
    const floatx4* xr = (const floatx4*)(x + node * FIN);
#pragma unroll 4
    for (int q = 0; q < FIN / 4; ++q) {
        floatx4 xv = __builtin_nontemporal_load(xr + q);
        int k = q * 4;
#pragma unroll
        for (int f = 0; f < HID; ++f) acc[f] += xv.x * sW[(k + 0) * HID + f];
#pragma unroll
        for (int f = 0; f < HID; ++f) acc[f] += xv.y * sW[(k + 1) * HID + f];
#pragma unroll
        for (int f = 0; f < HID; ++f) acc[f] += xv.z * sW[(k + 2) * HID + f];
#pragma unroll
        for (int f = 0; f < HID; ++f) acc[f] += xv.w * sW[(k + 3) * HID + f];
    }
    uint32_t* orow = (uint32_t*)t + (size_t)node * ROWD;
#pragma unroll
    for (int m = 0; m < HID / 2; ++m) {
        __half2 hh = __floats2half2_rn(acc[2 * m], acc[2 * m + 1]);
        orow[m] = *reinterpret_cast<uint32_t*>(&hh);
    }
}

// ================= radix CSR build (no global data atomics) =================
__global__ __launch_bounds__(BLK1T) void k_p1count(const int* __restrict__ dst,
                                                   int* __restrict__ ghist) {
    __shared__ int h[NB1];
    for (int i = threadIdx.x; i < NB1; i += BLK1T) h[i] = 0;
    __syncthreads();
    int lb = swz_blk(blockIdx.x);
    int base = lb * E1;
    for (int i = threadIdx.x; i < E1; i += BLK1T) {
        int d = __builtin_nontemporal_load(dst + base + i);
        atomicAdd(&h[d >> BSH], 1);
    }
    __syncthreads();
    for (int b = threadIdx.x; b < NB1; b += BLK1T)
        ghist[b * NBLK1 + lb] = h[b];
}

__global__ __launch_bounds__(256) void k_breduceB(const int* __restrict__ ghist,
                                                  int* __restrict__ bsum) {
    int bin = blockIdx.x;
    int t = threadIdx.x;
    int s = ghist[bin * NBLK1 + t];
    __shared__ int r[256];
    r[t] = s;
    __syncthreads();
    for (int o = 128; o > 0; o >>= 1) {
        if (t < o) r[t] += r[t + o];
        __syncthreads();
    }
    if (t == 0) bsum[bin] = r[0];
}

__global__ __launch_bounds__(256) void k_bscanB(const int* __restrict__ bsum,
                                                int* __restrict__ bstart) {
    __shared__ int s[NB1];
    for (int i = threadIdx.x; i < NB1; i += 256) s[i] = bsum[i];
    __syncthreads();
    if (threadIdx.x == 0) {
        int acc = 0;
        for (int i = 0; i < NB1; ++i) { int v = s[i]; s[i] = acc; acc += v; }
    }
    __syncthreads();
    for (int i = threadIdx.x; i < NB1; i += 256) bstart[i] = s[i];
    if (threadIdx.x == 0) bstart[NB1] = NE;
}

__global__ __launch_bounds__(256) void k_bbase(const int* __restrict__ ghist,
                                               const int* __restrict__ bstart,
                                               int* __restrict__ gbase) {
    int bin = blockIdx.x;
    int t = threadIdx.x;
    int v = ghist[bin * NBLK1 + t];
    __shared__ int tsum[256];
    tsum[t] = v;
    __syncthreads();
    for (int d = 1; d < 256; d <<= 1) {
        int add = (t >= d) ? tsum[t - d] : 0;
        __syncthreads();
        tsum[t] += add;
        __syncthreads();
    }
    gbase[(size_t)t * NB1P + bin] = tsum[t] - v + bstart[bin];
}

__global__ __launch_bounds__(BLK1T) void k_p1scatter(const int* __restrict__ src,
                                                     const int* __restrict__ dst,
                                                     const float* __restrict__ w,
                                                     const int* __restrict__ gbase,
                                                     int2* __restrict__ part) {
    __shared__ int cur[NB1];
    int t = threadIdx.x;
    int lb = swz_blk(blockIdx.x);
    for (int b = t; b < NB1; b += BLK1T) cur[b] = gbase[(size_t)lb * NB1P + b];
    __syncthreads();
    int base = lb * E1;
    for (int i = t; i < E1; i += BLK1T) {
        int e = base + i;
        int d = __builtin_nontemporal_load(dst + e);
        int s = __builtin_nontemporal_load(src + e);
        float wt = __builtin_nontemporal_load(w + e);
        int b = d >> BSH;
        int pos = atomicAdd(&cur[b], 1);
        part[pos] = make_int2(s | ((d & 255) << 17), __float_as_int(wt));
    }
}

// per-bucket counting sort; two half-staged passes for coalesced csr writes
__global__ __launch_bounds__(1024) void k_p2(const int2* __restrict__ part,
                                             const int* __restrict__ bstart,
                                             int2* __restrict__ csr,
                                             int* __restrict__ off) {
    int b = blockIdx.x;
    int lo = bstart[b], hi = bstart[b + 1];
    int n = hi - lo;
    int t = threadIdx.x;
    __shared__ int hist[256], tsum[256], cur[256];
    __shared__ int s_n0;
    __shared__ int2 stage[P2CAP];
    if (t < 256) hist[t] = 0;
    __syncthreads();
    for (int i = lo + t; i < hi; i += 1024) {
        int v = __builtin_nontemporal_load(&part[i].x);
        atomicAdd(&hist[(v >> 17) & 255], 1);
    }
    __syncthreads();
    int a = 0;
    if (t < 256) { a = hist[t]; tsum[t] = a; }
    __syncthreads();
    for (int d = 1; d < 256; d <<= 1) {
        int add = (t >= d && t < 256) ? tsum[t - d] : 0;
        __syncthreads();
        if (t < 256) tsum[t] += add;
        __syncthreads();
    }
    if (t < 256) {
        int excl = tsum[t] - a;
        cur[t] = excl;                    // bucket-relative
        int node = (b << BSH) + t;
        if (node < NN) off[node] = lo + excl;
    }
    if (t == 0) s_n0 = tsum[127];
    if (b == NB1 - 1 && t == 0) off[NN] = NE;
    __syncthreads();
    int n0 = s_n0;
    int n1 = n - n0;
    const long long* pp = (const long long*)part;

    if (n0 <= P2CAP) {
        for (int i = lo + t; i < hi; i += 1024) {
            long long pv = __builtin_nontemporal_load(pp + i);
            int px = (int)pv;
            int ld = (px >> 17) & 255;
            if (ld < 128) {
                int pos = atomicAdd(&cur[ld], 1);
                stage[pos] = make_int2(px & 0x1FFFF, (int)(pv >> 32));
            }
        }
        __syncthreads();
        for (int k = t; k < n0; k += 1024) csr[lo + k] = stage[k];
    } else {
        for (int i = lo + t; i < hi; i += 1024) {
            long long pv = __builtin_nontemporal_load(pp + i);
            int px = (int)pv;
            int ld = (px >> 17) & 255;
            if (ld < 128) {
                int pos = atomicAdd(&cur[ld], 1);
                csr[lo + pos] = make_int2(px & 0x1FFFF, (int)(pv >> 32));
            }
        }
    }
    __syncthreads();

    if (n1 <= P2CAP) {
        for (int i = lo + t; i < hi; i += 1024) {
            long long pv = __builtin_nontemporal_load(pp + i);
            int px = (int)pv;
            int ld = (px >> 17) & 255;
            if (ld >= 128) {
                int pos = atomicAdd(&cur[ld], 1);
                stage[pos - n0] = make_int2(px & 0x1FFFF, (int)(pv >> 32));
            }
        }
        __syncthreads();
        for (int k = t; k < n1; k += 1024) csr[lo + n0 + k] = stage[k];
    } else {
        for (int i = lo + t; i < hi; i += 1024) {
            long long pv = __builtin_nontemporal_load(pp + i);
            int px = (int)pv;
            int ld = (px >> 17) & 255;
            if (ld >= 128) {
                int pos = atomicAdd(&cur[ld], 1);
                csr[lo + pos] = make_int2(px & 0x1FFFF, (int)(pv >> 32));
            }
        }
    }
}

// ---------------- gather helper: 3 aligned probes, direct unpack ----------------
#define UNP(word, base)                                                     \
    {                                                                       \
        __half2 hh_ = *reinterpret_cast<const __half2*>(&(word));           \
        float2 f_ = __half22float2(hh_);                                    \
        acc[(base)] += wt * f_.x;                                           \
        acc[(base) + 1] += wt * f_.y;                                       \
    }

__device__ __forceinline__ void gather_row(const __half* __restrict__ tin,
                                           int srcn, float wt, float* acc) {
    const uint32_t* r = (const uint32_t*)tin + (size_t)srcn * ROWD;
    uint4 u0 = *(const uint4*)r;
    uint4 u1 = *(const uint4*)(r + 4);
    uint2 u2 = *(const uint2*)(r + 8);
    UNP(u0.x, 0)  UNP(u0.y, 2)  UNP(u0.z, 4)  UNP(u0.w, 6)
    UNP(u1.x, 8)  UNP(u1.y, 10) UNP(u1.z, 12) UNP(u1.w, 14)
    UNP(u2.x, 16) UNP(u2.y, 18)
}

// ---------------- Fused layer: 8 lanes/node, batched csr loads, split MLP ----------------
// csr loads are PLAIN (not NT): csr is reused by 3 layers -> let L2/L3 retain it.
template <bool LAST>
__global__ __launch_bounds__(256) void k_layer(const int* __restrict__ off,
                                               const int2* __restrict__ csr,
                                               const __half* __restrict__ tin,
                                               const float* __restrict__ ba,
                                               const float* __restrict__ Wb,
                                               const float* __restrict__ bb,
                                               const float* __restrict__ Wnext,
                                               __half* __restrict__ tout) {
    __shared__ float sWb[HID * HID];
    __shared__ float sWn[HID * HID];
    __shared__ float sba[HID], sbb[HID];
    for (int i = threadIdx.x; i < HID * HID; i += blockDim.x) {
        sWb[i] = Wb[i];
        sWn[i] = LAST ? ((i / HID == i % HID) ? 1.f : 0.f) : Wnext[i];
    }
    if (threadIdx.x < HID) {
        sba[threadIdx.x] = ba[threadIdx.x];
        sbb[threadIdx.x] = bb[threadIdx.x];
    }
    __syncthreads();

    int tid = blockIdx.x * blockDim.x + threadIdx.x;
    int node = tid >> 3;
    int j = tid & 7;
    if (node >= NN) return;
    int lo = off[node], hi = off[node + 1];

    float acc[HID];
#pragma unroll
    for (int f = 0; f < HID; ++f) acc[f] = 0.f;

    const long long* pc = (const long long*)csr;
    for (int base = lo + j; base < hi; base += 32) {
        int i1 = base + 8, i2 = base + 16, i3 = base + 24;
        long long e0 = pc[base];
        long long e1 = pc[i1 < hi ? i1 : base];
        long long e2 = pc[i2 < hi ? i2 : base];
        long long e3 = pc[i3 < hi ? i3 : base];
        float w0 = __int_as_float((int)(e0 >> 32));
        float w1 = (i1 < hi) ? __int_as_float((int)(e1 >> 32)) : 0.f;
        float w2 = (i2 < hi) ? __int_as_float((int)(e2 >> 32)) : 0.f;
        float w3 = (i3 < hi) ? __int_as_float((int)(e3 >> 32)) : 0.f;
        gather_row(tin, ((int)e0) & 0x1FFFF, w0, acc);
        gather_row(tin, ((int)e1) & 0x1FFFF, w1, acc);
        gather_row(tin, ((int)e2) & 0x1FFFF, w2, acc);
        gather_row(tin, ((int)e3) & 0x1FFFF, w3, acc);
    }

#pragma unroll
    for (int f = 0; f < HID; ++f) {
        acc[f] += __shfl_xor(acc[f], 1);
        acc[f] += __shfl_xor(acc[f], 2);
        acc[f] += __shfl_xor(acc[f], 4);
    }

#pragma unroll
    for (int f = 0; f < HID; ++f) acc[f] = fmaxf(acc[f] + sba[f], 0.f);

    bool has3 = (j < 4);
    int k0 = j, k1 = j + 8, k2 = has3 ? (j + 16) : j;
    float z2a = sbb[k0], z2b = sbb[k1], z2c = sbb[k2];
#pragma unroll
    for (int m = 0; m < HID; ++m) {
        float z = acc[m];
        z2a += z * sWb[m * HID + k0];
        z2b += z * sWb[m * HID + k1];
        z2c += z * sWb[m * HID + k2];
    }
    z2a = fmaxf(z2a, 0.f);
    z2b = fmaxf(z2b, 0.f);
    z2c = has3 ? fmaxf(z2c, 0.f) : 0.f;

    float ssp = z2a * z2a + z2b * z2b + z2c * z2c;
    ssp += __shfl_xor(ssp, 1);
    ssp += __shfl_xor(ssp, 2);
    ssp += __shfl_xor(ssp, 4);
    float scale = 1.f / fmaxf(sqrtf(ssp), 1e-12f);
    z2a *= scale; z2b *= scale; z2c *= scale;

    float rp[HID];
#pragma unroll
    for (int fo = 0; fo < HID; ++fo)
        rp[fo] = z2a * sWn[k0 * HID + fo] + z2b * sWn[k1 * HID + fo] + z2c * sWn[k2 * HID + fo];
#pragma unroll
    for (int fo = 0; fo < HID; ++fo) {
        rp[fo] += __shfl_xor(rp[fo], 1);
        rp[fo] += __shfl_xor(rp[fo], 2);
        rp[fo] += __shfl_xor(rp[fo], 4);
    }

    float o0 = 0.f, o1 = 0.f, p0 = 0.f, p1 = 0.f;
#pragma unroll
    for (int m = 0; m < HID / 2; ++m) {
        if (j == m)     { o0 = rp[2 * m]; o1 = rp[2 * m + 1]; }
        if (j + 8 == m) { p0 = rp[2 * m]; p1 = rp[2 * m + 1]; }
    }
    uint32_t* orow = (uint32_t*)tout + (size_t)node * ROWD;
    {
        __half2 hh = __floats2half2_rn(o0, o1);
        orow[j] = *reinterpret_cast<uint32_t*>(&hh);
    }
    if (j < 2) {
        __half2 hh = __floats2half2_rn(p0, p1);
        orow[j + 8] = *reinterpret_cast<uint32_t*>(&hh);
    }
}

// ---------------- Pooling + head (padded f16 h) ----------------
__global__ __launch_bounds__(256) void k_pool_h(const __half* __restrict__ h,
                                                const int* __restrict__ batch,
                                                const float* __restrict__ Wlin,
                                                const float* __restrict__ blin,
                                                float* __restrict__ out) {
    int g = blockIdx.x;
    __shared__ int s_lo, s_hi;
    if (threadIdx.x == 0) {
        int a = 0, b = NN;
        while (a < b) { int m = (a + b) >> 1; if (batch[m] < g) a = m + 1; else b = m; }
        s_lo = a;
        b = NN;
        while (a < b) { int m = (a + b) >> 1; if (batch[m] < g + 1) a = m + 1; else b = m; }
        s_hi = a;
    }
    __syncthreads();
    int lo = s_lo, hi = s_hi;

    float sm[HID], mx[HID];
#pragma unroll
    for (int f = 0; f < HID; ++f) { sm[f] = 0.f; mx[f] = 0.f; }

    for (int i = lo + threadIdx.x; i < hi; i += blockDim.x) {
        const uint32_t* r = (const uint32_t*)h + (size_t)i * ROWD;
        uint4 u0 = *(const uint4*)r;
        uint4 u1 = *(const uint4*)(r + 4);
        uint2 u2 = *(const uint2*)(r + 8);
        uint32_t ws[10] = {u0.x, u0.y, u0.z, u0.w, u1.x, u1.y, u1.z, u1.w, u2.x, u2.y};
#pragma unroll
        for (int m = 0; m < 10; ++m) {
            __half2 hh = *reinterpret_cast<const __half2*>(&ws[m]);
            float2 f = __half22float2(hh);
            sm[2 * m + 0] += f.x; mx[2 * m + 0] = fmaxf(mx[2 * m + 0], f.x);
            sm[2 * m + 1] += f.y; mx[2 * m + 1] = fmaxf(mx[2 * m + 1], f.y);
        }
    }

#pragma unroll
    for (int f = 0; f < HID; ++f) {
        float s = sm[f], m = mx[f];
        for (int off = 32; off > 0; off >>= 1) {
            s += __shfl_down(s, off);
            m = fmaxf(m, __shfl_down(m, off));
        }
        sm[f] = s; mx[f] = m;
    }

    __shared__ float psum[4][HID], pmax[4][HID];
    int wave = threadIdx.x >> 6;
    int lane = threadIdx.x & 63;
    if (lane == 0) {
#pragma unroll
        for (int f = 0; f < HID; ++f) { psum[wave][f] = sm[f]; pmax[wave][f] = mx[f]; }
    }
    __syncthreads();

    __shared__ float fsum[HID], fmax_[HID];
    if (threadIdx.x < HID) {
        int f = threadIdx.x;
        fsum[f] = psum[0][f] + psum[1][f] + psum[2][f] + psum[3][f];
        fmax_[f] = fmaxf(fmaxf(pmax[0][f], pmax[1][f]), fmaxf(pmax[2][f], pmax[3][f]));
    }
    __syncthreads();

    if (threadIdx.x < NC) {
        int c = threadIdx.x;
        float cnt = (float)(hi - lo);
        float inv = 1.f / fmaxf(cnt, 1.f);
        float o = blin[c];
#pragma unroll
        for (int f = 0; f < HID; ++f) {
            o += fmax_[f] * Wlin[f * NC + c];
            o += (fsum[f] * inv) * Wlin[(HID + f) * NC + c];
        }
        out[g * NC + c] = o;
    }
}

// ================= fp32 fallback path (ws too small) =================
__global__ __launch_bounds__(256) void k_in_gemm(const float* __restrict__ x,
                                                 const float* __restrict__ W,
                                                 float* __restrict__ t) {
    __shared__ float sW[FIN * HID];
    for (int i = threadIdx.x; i < FIN * HID; i += blockDim.x) sW[i] = W[i];
    __syncthreads();
    int node = blockIdx.x * blockDim.x + threadIdx.x;
    if (node >= NN) return;
    float acc[HID];
#pragma unroll
    for (int f = 0; f < HID; ++f) acc[f] = 0.f;
    const float4* xr = (const float4*)(x + node * FIN);
    for (int q = 0; q < FIN / 4; ++q) {
        float4 xv = xr[q];
        int k = q * 4;
#pragma unroll
        for (int f = 0; f < HID; ++f)
            acc[f] += xv.x * sW[k * HID + f] + xv.y * sW[(k + 1) * HID + f] +
                      xv.z * sW[(k + 2) * HID + f] + xv.w * sW[(k + 3) * HID + f];
    }
    float4* tr = (float4*)(t + node * HID);
#pragma unroll
    for (int q = 0; q < HID / 4; ++q) {
        float4 v;
        v.x = acc[q * 4 + 0]; v.y = acc[q * 4 + 1];
        v.z = acc[q * 4 + 2]; v.w = acc[q * 4 + 3];
        tr[q] = v;
    }
}

__global__ __launch_bounds__(256) void k_scatter(const int* __restrict__ src,
                                                 const int* __restrict__ dst,
                                                 const float* __restrict__ w,
                                                 const float* __restrict__ t,
                                                 float* __restrict__ agg) {
    int e = blockIdx.x * blockDim.x + threadIdx.x;
    if (e >= NE) return;
    int s = src[e];
    int d = dst[e];
    float wt = w[e];
    const float4* tr = (const float4*)(t + (long)s * HID);
    float* ar = agg + (long)d * HID;
#pragma unroll
    for (int q = 0; q < HID / 4; ++q) {
        float4 v = tr[q];
        atomicAdd(ar + q * 4 + 0, v.x * wt);
        atomicAdd(ar + q * 4 + 1, v.y * wt);
        atomicAdd(ar + q * 4 + 2, v.z * wt);
        atomicAdd(ar + q * 4 + 3, v.w * wt);
    }
}

template <bool LAST>
__global__ __launch_bounds__(256) void k_node(const float* agg,
                                              const float* __restrict__ ba,
                                              const float* __restrict__ Wb,
                                              const float* __restrict__ bb,
                                              const float* __restrict__ Wnext,
                                              float* out) {
    __shared__ float sWb[HID * HID];
    __shared__ float sWn[HID * HID];
    __shared__ float sba[HID], sbb[HID];
    for (int i = threadIdx.x; i < HID * HID; i += blockDim.x) {
        sWb[i] = Wb[i];
        if (!LAST) sWn[i] = Wnext[i];
    }
    if (threadIdx.x < HID) {
        sba[threadIdx.x] = ba[threadIdx.x];
        sbb[threadIdx.x] = bb[threadIdx.x];
    }
    __syncthreads();
    int node = blockIdx.x * blockDim.x + threadIdx.x;
    if (node >= NN) return;

    float z1[HID];
    const float4* ar = (const float4*)(agg + (long)node * HID);
#pragma unroll
    for (int q = 0; q < HID / 4; ++q) {
        float4 v = ar[q];
        z1[q * 4 + 0] = v.x; z1[q * 4 + 1] = v.y;
        z1[q * 4 + 2] = v.z; z1[q * 4 + 3] = v.w;
    }
#pragma unroll
    for (int f = 0; f < HID; ++f) z1[f] = fmaxf(z1[f] + sba[f], 0.f);

    float z2[HID];
#pragma unroll
    for (int fo = 0; fo < HID; ++fo) {
        float a = sbb[fo];
#pragma unroll
        for (int k = 0; k < HID; ++k) a += z1[k] * sWb[k * HID + fo];
        z2[fo] = fmaxf(a, 0.f);
    }
    float ss = 0.f;
#pragma unroll
    for (int f = 0; f < HID; ++f) ss += z2[f] * z2[f];
    float scale = 1.f / fmaxf(sqrtf(ss), 1e-12f);
#pragma unroll
    for (int f = 0; f < HID; ++f) z2[f] *= scale;

    float res[HID];
    if (LAST) {
#pragma unroll
        for (int f = 0; f < HID; ++f) res[f] = z2[f];
    } else {
#pragma unroll
        for (int fo = 0; fo < HID; ++fo) {
            float a = 0.f;
#pragma unroll
            for (int k = 0; k < HID; ++k) a += z2[k] * sWn[k * HID + fo];
            res[fo] = a;
        }
    }
    float4* orow = (float4*)(out + (long)node * HID);
#pragma unroll
    for (int q = 0; q < HID / 4; ++q) {
        float4 v;
        v.x = res[q * 4 + 0]; v.y = res[q * 4 + 1];
        v.z = res[q * 4 + 2]; v.w = res[q * 4 + 3];
        orow[q] = v;
    }
}

__global__ __launch_bounds__(256) void k_pool(const float* __restrict__ h,
                                              const int* __restrict__ batch,
                                              const float* __restrict__ Wlin,
                                              const float* __restrict__ blin,
                                              float* __restrict__ out) {
    int g = blockIdx.x;
    __shared__ int s_lo, s_hi;
    if (threadIdx.x == 0) {
        int a = 0, b = NN;
        while (a < b) { int m = (a + b) >> 1; if (batch[m] < g) a = m + 1; else b = m; }
        s_lo = a;
        b = NN;
        while (a < b) { int m = (a + b) >> 1; if (batch[m] < g + 1) a = m + 1; else b = m; }
        s_hi = a;
    }
    __syncthreads();
    int lo = s_lo, hi = s_hi;
    float sm[HID], mx[HID];
#pragma unroll
    for (int f = 0; f < HID; ++f) { sm[f] = 0.f; mx[f] = 0.f; }
    for (int i = lo + threadIdx.x; i < hi; i += blockDim.x) {
        const float4* hr = (const float4*)(h + (long)i * HID);
#pragma unroll
        for (int q = 0; q < HID / 4; ++q) {
            float4 v = hr[q];
            sm[q * 4 + 0] += v.x; mx[q * 4 + 0] = fmaxf(mx[q * 4 + 0], v.x);
            sm[q * 4 + 1] += v.y; mx[q * 4 + 1] = fmaxf(mx[q * 4 + 1], v.y);
            sm[q * 4 + 2] += v.z; mx[q * 4 + 2] = fmaxf(mx[q * 4 + 2], v.z);
            sm[q * 4 + 3] += v.w; mx[q * 4 + 3] = fmaxf(mx[q * 4 + 3], v.w);
        }
    }
#pragma unroll
    for (int f = 0; f < HID; ++f) {
        float s = sm[f], m = mx[f];
        for (int off = 32; off > 0; off >>= 1) {
            s += __shfl_down(s, off);
            m = fmaxf(m, __shfl_down(m, off));
        }
        sm[f] = s; mx[f] = m;
    }
    __shared__ float psum[4][HID], pmax[4][HID];
    int wave = threadIdx.x >> 6;
    int lane = threadIdx.x & 63;
    if (lane == 0) {
#pragma unroll
        for (int f = 0; f < HID; ++f) { psum[wave][f] = sm[f]; pmax[wave][f] = mx[f]; }
    }
    __syncthreads();
    __shared__ float fsum[HID], fmax_[HID];
    if (threadIdx.x < HID) {
        int f = threadIdx.x;
        fsum[f] = psum[0][f] + psum[1][f] + psum[2][f] + psum[3][f];
        fmax_[f] = fmaxf(fmaxf(pmax[0][f], pmax[1][f]), fmaxf(pmax[2][f], pmax[3][f]));
    }
    __syncthreads();
    if (threadIdx.x < NC) {
        int c = threadIdx.x;
        float cnt = (float)(hi - lo);
        float inv = 1.f / fmaxf(cnt, 1.f);
        float o = blin[c];
#pragma unroll
        for (int f = 0; f < HID; ++f) {
            o += fmax_[f] * Wlin[f * NC + c];
            o += (fsum[f] * inv) * Wlin[(HID + f) * NC + c];
        }
        out[g * NC + c] = o;
    }
}

extern "C" void kernel_launch(void* const* d_in, const int* in_sizes, int n_in,
                              void* d_out, int out_size, void* d_ws, size_t ws_size,
                              hipStream_t stream) {
    const float* x   = (const float*)d_in[0];
    const int*   ei  = (const int*)d_in[1];
    const int*   bat = (const int*)d_in[2];
    const float* ew  = (const float*)d_in[3];
    const float* W1a = (const float*)d_in[4];
    const float* b1a = (const float*)d_in[5];
    const float* W1b = (const float*)d_in[6];
    const float* b1b = (const float*)d_in[7];
    const float* W2a = (const float*)d_in[8];
    const float* b2a = (const float*)d_in[9];
    const float* W2b = (const float*)d_in[10];
    const float* b2b = (const float*)d_in[11];
    const float* W3a = (const float*)d_in[12];
    const float* b3a = (const float*)d_in[13];
    const float* W3b = (const float*)d_in[14];
    const float* b3b = (const float*)d_in[15];
    const float* Wlin = (const float*)d_in[16];
    const float* blin = (const float*)d_in[17];

    const int* src = ei;
    const int* dst = ei + NE;

    dim3 gN((NN + 255) / 256);
    dim3 gQ8(((size_t)NN * 8 + 255) / 256);   // 8 lanes per node

    size_t szT    = (size_t)NN * HID * sizeof(float);         // 8 MB (fallback)
    size_t szCsr  = (size_t)NE * sizeof(int2);                // 25.6 MB
    size_t szOff  = ((size_t)(NN + 1) * sizeof(int) + 15) & ~(size_t)15;
    size_t szGh   = (size_t)NB1 * NBLK1 * sizeof(int);        // 400 KB
    size_t szGb   = (size_t)NBLK1 * NB1P * sizeof(int);       // 401 KB
    size_t szSm   = 4096;
    size_t szTh   = (size_t)NN * (2 * ROWD) * sizeof(__half) / 2; // NN*ROWD dwords = 4.8 MB
    size_t szTbl  = (size_t)NN * ROWD * sizeof(uint32_t);     // 4.8 MB per table
    size_t szPart = szCsr > 2 * szTbl ? szCsr : 2 * szTbl;    // part ∪ (T0h,T1h)
    size_t need_radix = szCsr + szOff + szGh + szGb + 2 * szSm + szPart;
    (void)szTh;

    if (ws_size >= need_radix) {
        char* p = (char*)d_ws;
        int2* csr    = (int2*)p;  p += szCsr;
        int*  offv   = (int*)p;   p += szOff;
        int*  ghist  = (int*)p;   p += szGh;
        int*  gbase  = (int*)p;   p += szGb;
        int*  bsum   = (int*)p;   p += szSm;
        int*  bstart = (int*)p;   p += szSm;
        int2* part   = (int2*)p;             // dead after k_p2; then hosts T0h,T1h
        __half* T0h = (__half*)part;
        __half* T1h = T0h + (size_t)NN * (2 * ROWD) / 2 * 2;  // NN*ROWD dwords = NN*2*ROWD halfs... use dword math
        T1h = (__half*)((uint32_t*)part + (size_t)NN * ROWD);

        // ---- build CSR (two-level counting sort, once; reused by 3 layers) ----
        k_p1count<<<NBLK1, BLK1T, 0, stream>>>(dst, ghist);
        k_breduceB<<<NB1, 256, 0, stream>>>(ghist, bsum);
        k_bscanB<<<1, 256, 0, stream>>>(bsum, bstart);
        k_bbase<<<NB1, 256, 0, stream>>>(ghist, bstart, gbase);
        k_p1scatter<<<NBLK1, BLK1T, 0, stream>>>(src, dst, ew, gbase, part);
        k_p2<<<NB1, 1024, 0, stream>>>(part, bstart, csr, offv);

        // ---- fused layers (padded f16 rows, 3-probe gathers) ----
        k_in_gemm_h<<<gN, 256, 0, stream>>>(x, W1a, T0h);
        k_layer<false><<<gQ8, 256, 0, stream>>>(offv, csr, T0h, b1a, W1b, b1b, W2a, T1h);
        k_layer<false><<<gQ8, 256, 0, stream>>>(offv, csr, T1h, b2a, W2b, b2b, W3a, T0h);
        k_layer<true><<<gQ8, 256, 0, stream>>>(offv, csr, T0h, b3a, W3b, b3b, nullptr, T1h);

        k_pool_h<<<NG, 256, 0, stream>>>(T1h, bat, Wlin, blin, (float*)d_out);
    } else {
        // fallback: fp32 atomic scatter path
        char* p = (char*)d_ws;
        float* T0 = (float*)p;  p += szT;
        float* T1 = (float*)p;
        dim3 gE((NE + 255) / 256);

        k_in_gemm<<<gN, 256, 0, stream>>>(x, W1a, T0);
        (void)hipMemsetAsync(T1, 0, szT, stream);
        k_scatter<<<gE, 256, 0, stream>>>(src, dst, ew, T0, T1);
        k_node<false><<<gN, 256, 0, stream>>>(T1, b1a, W1b, b1b, W2a, T0);
        (void)hipMemsetAsync(T1, 0, szT, stream);
        k_scatter<<<gE, 256, 0, stream>>>(src, dst, ew, T0, T1);
        k_node<false><<<gN, 256, 0, stream>>>(T1, b2a, W2b, b2b, W3a, T0);
        (void)hipMemsetAsync(T1, 0, szT, stream);
        k_scatter<<<gE, 256, 0, stream>>>(src, dst, ew, T0, T1);
        k_node<true><<<gN, 256, 0, stream>>>(T1, b3a, W3b, b3b, nullptr, T0);
        k_pool<<<NG, 256, 0, stream>>>(T0, bat, Wlin, blin, (float*)d_out);
    }
}

// Round 18
// 252.019 us; speedup vs baseline: 1.0261x; 1.0261x over previous
//
#include <hip/hip_runtime.h>
#include <hip/hip_fp16.h>
#include <math.h>

#define NN 100000
#define NE 3200000
#define FIN 64
#define HID 20
#define NG 128
#define NC 10

// ---- two-level counting-sort params ----
#define BSH 8                 // nodes per bucket = 256
#define NB1 391               // ceil(NN / 256)
#define NB1P 392
#define NBLK1 256             // partition blocks: covers all 256 CUs
#define BLK1T 1024            // threads per partition block
#define E1 (NE / NBLK1)       // 12500 exactly
#define NXCD 8
#define P2CAP 6144            // half-bucket stage capacity (mean 4092 + 32 sigma)

typedef float floatx4 __attribute__((ext_vector_type(4)));

__device__ __forceinline__ int swz_blk(int bid) {
    return (bid & (NXCD - 1)) * (NBLK1 / NXCD) + (bid >> 3);
}

// ---------------- t0 = x @ W1a, stored f16  ----------------
__global__ __launch_bounds__(256) void k_in_gemm_h(const float* __restrict__ x,
                                                   const float* __restrict__ W,
                                                   __half* __restrict__ t) {
    __shared__ float sW[FIN * HID];
    for (int i = threadIdx.x; i < FIN * HID; i += blockDim.x) sW[i] = W[i];
    __syncthreads();
    int node = blockIdx.x * blockDim.x + threadIdx.x;
    if (node >= NN) return;
    float acc[HID];
#pragma unroll
    for (int f = 0; f < HID; ++f) acc[f] = 0.f;
    const floatx4* xr = (const floatx4*)(x + node * FIN);
#pragma unroll 4
    for (int q = 0; q < FIN / 4; ++q) {
        floatx4 xv = __builtin_nontemporal_load(xr + q);
        int k = q * 4;
#pragma unroll
        for (int f = 0; f < HID; ++f) acc[f] += xv.x * sW[(k + 0) * HID + f];
#pragma unroll
        for (int f = 0; f < HID; ++f) acc[f] += xv.y * sW[(k + 1) * HID + f];
#pragma unroll
        for (int f = 0; f < HID; ++f) acc[f] += xv.z * sW[(k + 2) * HID + f];
#pragma unroll
        for (int f = 0; f < HID; ++f) acc[f] += xv.w * sW[(k + 3) * HID + f];
    }
    uint32_t* orow = (uint32_t*)t + (size_t)node * (HID / 2);
#pragma unroll
    for (int m = 0; m < HID / 2; ++m) {
        __half2 hh = __floats2half2_rn(acc[2 * m], acc[2 * m + 1]);
        orow[m] = *reinterpret_cast<uint32_t*>(&hh);
    }
}

// ================= radix CSR build (no global data atomics) =================
__global__ __launch_bounds__(BLK1T) void k_p1count(const int* __restrict__ dst,
                                                   int* __restrict__ ghist) {
    __shared__ int h[NB1];
    for (int i = threadIdx.x; i < NB1; i += BLK1T) h[i] = 0;
    __syncthreads();
    int lb = swz_blk(blockIdx.x);
    int base = lb * E1;
    for (int i = threadIdx.x; i < E1; i += BLK1T) {
        int d = __builtin_nontemporal_load(dst + base + i);
        atomicAdd(&h[d >> BSH], 1);
    }
    __syncthreads();
    for (int b = threadIdx.x; b < NB1; b += BLK1T)
        ghist[b * NBLK1 + lb] = h[b];
}

// bucket totals: thread t owns partition-block t (256 threads)
__global__ __launch_bounds__(256) void k_breduceB(const int* __restrict__ ghist,
                                                  int* __restrict__ bsum) {
    int bin = blockIdx.x;
    int t = threadIdx.x;
    int s = ghist[bin * NBLK1 + t];
    __shared__ int r[256];
    r[t] = s;
    __syncthreads();
    for (int o = 128; o > 0; o >>= 1) {
        if (t < o) r[t] += r[t + o];
        __syncthreads();
    }
    if (t == 0) bsum[bin] = r[0];
}

__global__ __launch_bounds__(256) void k_bscanB(const int* __restrict__ bsum,
                                                int* __restrict__ bstart) {
    __shared__ int s[NB1];
    for (int i = threadIdx.x; i < NB1; i += 256) s[i] = bsum[i];
    __syncthreads();
    if (threadIdx.x == 0) {
        int acc = 0;
        for (int i = 0; i < NB1; ++i) { int v = s[i]; s[i] = acc; acc += v; }
    }
    __syncthreads();
    for (int i = threadIdx.x; i < NB1; i += 256) bstart[i] = s[i];
    if (threadIdx.x == 0) bstart[NB1] = NE;
}

// per-(block,bucket) base: thread t owns partition-block t (256 threads)
__global__ __launch_bounds__(256) void k_bbase(const int* __restrict__ ghist,
                                               const int* __restrict__ bstart,
                                               int* __restrict__ gbase) {
    int bin = blockIdx.x;
    int t = threadIdx.x;
    int v = ghist[bin * NBLK1 + t];
    __shared__ int tsum[256];
    tsum[t] = v;
    __syncthreads();
    for (int d = 1; d < 256; d <<= 1) {
        int add = (t >= d) ? tsum[t - d] : 0;
        __syncthreads();
        tsum[t] += add;
        __syncthreads();
    }
    gbase[(size_t)t * NB1P + bin] = tsum[t] - v + bstart[bin];
}

__global__ __launch_bounds__(BLK1T) void k_p1scatter(const int* __restrict__ src,
                                                     const int* __restrict__ dst,
                                                     const float* __restrict__ w,
                                                     const int* __restrict__ gbase,
                                                     int2* __restrict__ part) {
    __shared__ int cur[NB1];
    int t = threadIdx.x;
    int lb = swz_blk(blockIdx.x);
    for (int b = t; b < NB1; b += BLK1T) cur[b] = gbase[(size_t)lb * NB1P + b];
    __syncthreads();
    int base = lb * E1;
    for (int i = t; i < E1; i += BLK1T) {
        int e = base + i;
        int d = __builtin_nontemporal_load(dst + e);
        int s = __builtin_nontemporal_load(src + e);
        float wt = __builtin_nontemporal_load(w + e);
        int b = d >> BSH;
        int pos = atomicAdd(&cur[b], 1);
        part[pos] = make_int2(s | ((d & 255) << 17), __float_as_int(wt));
    }
}

// per-bucket counting sort; two half-staged passes for coalesced csr writes
__global__ __launch_bounds__(1024) void k_p2(const int2* __restrict__ part,
                                             const int* __restrict__ bstart,
                                             int2* __restrict__ csr,
                                             int* __restrict__ off) {
    int b = blockIdx.x;
    int lo = bstart[b], hi = bstart[b + 1];
    int n = hi - lo;
    int t = threadIdx.x;
    __shared__ int hist[256], tsum[256], cur[256];
    __shared__ int s_n0;
    __shared__ int2 stage[P2CAP];
    if (t < 256) hist[t] = 0;
    __syncthreads();
    for (int i = lo + t; i < hi; i += 1024) {
        int v = __builtin_nontemporal_load(&part[i].x);
        atomicAdd(&hist[(v >> 17) & 255], 1);
    }
    __syncthreads();
    int a = 0;
    if (t < 256) { a = hist[t]; tsum[t] = a; }
    __syncthreads();
    for (int d = 1; d < 256; d <<= 1) {
        int add = (t >= d && t < 256) ? tsum[t - d] : 0;
        __syncthreads();
        if (t < 256) tsum[t] += add;
        __syncthreads();
    }
    if (t < 256) {
        int excl = tsum[t] - a;
        cur[t] = excl;                    // bucket-relative
        int node = (b << BSH) + t;
        if (node < NN) off[node] = lo + excl;
    }
    if (t == 0) s_n0 = tsum[127];         // entries in lower half (nodes 0..127)
    if (b == NB1 - 1 && t == 0) off[NN] = NE;
    __syncthreads();
    int n0 = s_n0;
    int n1 = n - n0;
    const long long* pp = (const long long*)part;

    // ---- pass A: lower-half nodes (ld < 128) ----
    if (n0 <= P2CAP) {
        for (int i = lo + t; i < hi; i += 1024) {
            long long pv = __builtin_nontemporal_load(pp + i);
            int px = (int)pv;
            int ld = (px >> 17) & 255;
            if (ld < 128) {
                int pos = atomicAdd(&cur[ld], 1);
                stage[pos] = make_int2(px & 0x1FFFF, (int)(pv >> 32));
            }
        }
        __syncthreads();
        for (int k = t; k < n0; k += 1024) csr[lo + k] = stage[k];
    } else {
        for (int i = lo + t; i < hi; i += 1024) {
            long long pv = __builtin_nontemporal_load(pp + i);
            int px = (int)pv;
            int ld = (px >> 17) & 255;
            if (ld < 128) {
                int pos = atomicAdd(&cur[ld], 1);
                csr[lo + pos] = make_int2(px & 0x1FFFF, (int)(pv >> 32));
            }
        }
    }
    __syncthreads();

    // ---- pass B: upper-half nodes (ld >= 128) ----
    if (n1 <= P2CAP) {
        for (int i = lo + t; i < hi; i += 1024) {
            long long pv = __builtin_nontemporal_load(pp + i);
            int px = (int)pv;
            int ld = (px >> 17) & 255;
            if (ld >= 128) {
                int pos = atomicAdd(&cur[ld], 1);
                stage[pos - n0] = make_int2(px & 0x1FFFF, (int)(pv >> 32));
            }
        }
        __syncthreads();
        for (int k = t; k < n1; k += 1024) csr[lo + n0 + k] = stage[k];
    } else {
        for (int i = lo + t; i < hi; i += 1024) {
            long long pv = __builtin_nontemporal_load(pp + i);
            int px = (int)pv;
            int ld = (px >> 17) & 255;
            if (ld >= 128) {
                int pos = atomicAdd(&cur[ld], 1);
                csr[lo + pos] = make_int2(px & 0x1FFFF, (int)(pv >> 32));
            }
        }
    }
}

// ---------------- gather helper ----------------
__device__ __forceinline__ void gather_row(const __half* __restrict__ tin,
                                           int srcn, float wt, float* acc) {
    const uint2* r = (const uint2*)tin + (size_t)srcn * 5;
#pragma unroll
    for (int k = 0; k < 5; ++k) {
        uint2 u = r[k];
        __half2 h0 = *reinterpret_cast<const __half2*>(&u.x);
        __half2 h1 = *reinterpret_cast<const __half2*>(&u.y);
        float2 f0 = __half22float2(h0);
        float2 f1 = __half22float2(h1);
        acc[4 * k + 0] += wt * f0.x;
        acc[4 * k + 1] += wt * f0.y;
        acc[4 * k + 2] += wt * f1.x;
        acc[4 * k + 3] += wt * f1.y;
    }
}

// ---------------- Fused layer: 8 lanes/node, batched csr loads, split MLP ----------------
// csr loads are PLAIN (not NT): csr is reused by 3 layers -> let L2/L3 retain it.
template <bool LAST>
__global__ __launch_bounds__(256) void k_layer(const int* __restrict__ off,
                                               const int2* __restrict__ csr,
                                               const __half* __restrict__ tin,
                                               const float* __restrict__ ba,
                                               const float* __restrict__ Wb,
                                               const float* __restrict__ bb,
                                               const float* __restrict__ Wnext,
                                               __half* __restrict__ tout) {
    __shared__ float sWb[HID * HID];
    __shared__ float sWn[HID * HID];
    __shared__ float sba[HID], sbb[HID];
    for (int i = threadIdx.x; i < HID * HID; i += blockDim.x) {
        sWb[i] = Wb[i];
        sWn[i] = LAST ? ((i / HID == i % HID) ? 1.f : 0.f) : Wnext[i];
    }
    if (threadIdx.x < HID) {
        sba[threadIdx.x] = ba[threadIdx.x];
        sbb[threadIdx.x] = bb[threadIdx.x];
    }
    __syncthreads();

    int tid = blockIdx.x * blockDim.x + threadIdx.x;
    int node = tid >> 3;
    int j = tid & 7;
    if (node >= NN) return;
    int lo = off[node], hi = off[node + 1];

    float acc[HID];
#pragma unroll
    for (int f = 0; f < HID; ++f) acc[f] = 0.f;

    const long long* pc = (const long long*)csr;
    for (int base = lo + j; base < hi; base += 32) {
        int i1 = base + 8, i2 = base + 16, i3 = base + 24;
        long long e0 = pc[base];
        long long e1 = pc[i1 < hi ? i1 : base];
        long long e2 = pc[i2 < hi ? i2 : base];
        long long e3 = pc[i3 < hi ? i3 : base];
        float w0 = __int_as_float((int)(e0 >> 32));
        float w1 = (i1 < hi) ? __int_as_float((int)(e1 >> 32)) : 0.f;
        float w2 = (i2 < hi) ? __int_as_float((int)(e2 >> 32)) : 0.f;
        float w3 = (i3 < hi) ? __int_as_float((int)(e3 >> 32)) : 0.f;
        gather_row(tin, ((int)e0) & 0x1FFFF, w0, acc);
        gather_row(tin, ((int)e1) & 0x1FFFF, w1, acc);
        gather_row(tin, ((int)e2) & 0x1FFFF, w2, acc);
        gather_row(tin, ((int)e3) & 0x1FFFF, w3, acc);
    }

#pragma unroll
    for (int f = 0; f < HID; ++f) {
        acc[f] += __shfl_xor(acc[f], 1);
        acc[f] += __shfl_xor(acc[f], 2);
        acc[f] += __shfl_xor(acc[f], 4);
    }

#pragma unroll
    for (int f = 0; f < HID; ++f) acc[f] = fmaxf(acc[f] + sba[f], 0.f);

    bool has3 = (j < 4);
    int k0 = j, k1 = j + 8, k2 = has3 ? (j + 16) : j;
    float z2a = sbb[k0], z2b = sbb[k1], z2c = sbb[k2];
#pragma unroll
    for (int m = 0; m < HID; ++m) {
        float z = acc[m];
        z2a += z * sWb[m * HID + k0];
        z2b += z * sWb[m * HID + k1];
        z2c += z * sWb[m * HID + k2];
    }
    z2a = fmaxf(z2a, 0.f);
    z2b = fmaxf(z2b, 0.f);
    z2c = has3 ? fmaxf(z2c, 0.f) : 0.f;

    float ssp = z2a * z2a + z2b * z2b + z2c * z2c;
    ssp += __shfl_xor(ssp, 1);
    ssp += __shfl_xor(ssp, 2);
    ssp += __shfl_xor(ssp, 4);
    float scale = 1.f / fmaxf(sqrtf(ssp), 1e-12f);
    z2a *= scale; z2b *= scale; z2c *= scale;

    float rp[HID];
#pragma unroll
    for (int fo = 0; fo < HID; ++fo)
        rp[fo] = z2a * sWn[k0 * HID + fo] + z2b * sWn[k1 * HID + fo] + z2c * sWn[k2 * HID + fo];
#pragma unroll
    for (int fo = 0; fo < HID; ++fo) {
        rp[fo] += __shfl_xor(rp[fo], 1);
        rp[fo] += __shfl_xor(rp[fo], 2);
        rp[fo] += __shfl_xor(rp[fo], 4);
    }

    float o0 = 0.f, o1 = 0.f, p0 = 0.f, p1 = 0.f;
#pragma unroll
    for (int m = 0; m < HID / 2; ++m) {
        if (j == m)     { o0 = rp[2 * m]; o1 = rp[2 * m + 1]; }
        if (j + 8 == m) { p0 = rp[2 * m]; p1 = rp[2 * m + 1]; }
    }
    uint32_t* orow = (uint32_t*)tout + (size_t)node * (HID / 2);
    {
        __half2 hh = __floats2half2_rn(o0, o1);
        orow[j] = *reinterpret_cast<uint32_t*>(&hh);
    }
    if (j < 2) {
        __half2 hh = __floats2half2_rn(p0, p1);
        orow[j + 8] = *reinterpret_cast<uint32_t*>(&hh);
    }
}

// ---------------- Pooling + head (f16 h) ----------------
__global__ __launch_bounds__(256) void k_pool_h(const __half* __restrict__ h,
                                                const int* __restrict__ batch,
                                                const float* __restrict__ Wlin,
                                                const float* __restrict__ blin,
                                                float* __restrict__ out) {
    int g = blockIdx.x;
    __shared__ int s_lo, s_hi;
    if (threadIdx.x == 0) {
        int a = 0, b = NN;
        while (a < b) { int m = (a + b) >> 1; if (batch[m] < g) a = m + 1; else b = m; }
        s_lo = a;
        b = NN;
        while (a < b) { int m = (a + b) >> 1; if (batch[m] < g + 1) a = m + 1; else b = m; }
        s_hi = a;
    }
    __syncthreads();
    int lo = s_lo, hi = s_hi;

    float sm[HID], mx[HID];
#pragma unroll
    for (int f = 0; f < HID; ++f) { sm[f] = 0.f; mx[f] = 0.f; }

    for (int i = lo + threadIdx.x; i < hi; i += blockDim.x) {
        const uint2* hr = (const uint2*)h + (size_t)i * 5;
#pragma unroll
        for (int k = 0; k < 5; ++k) {
            uint2 u = hr[k];
            __half2 h0 = *reinterpret_cast<const __half2*>(&u.x);
            __half2 h1 = *reinterpret_cast<const __half2*>(&u.y);
            float2 f0 = __half22float2(h0);
            float2 f1 = __half22float2(h1);
            sm[4 * k + 0] += f0.x; mx[4 * k + 0] = fmaxf(mx[4 * k + 0], f0.x);
            sm[4 * k + 1] += f0.y; mx[4 * k + 1] = fmaxf(mx[4 * k + 1], f0.y);
            sm[4 * k + 2] += f1.x; mx[4 * k + 2] = fmaxf(mx[4 * k + 2], f1.x);
            sm[4 * k + 3] += f1.y; mx[4 * k + 3] = fmaxf(mx[4 * k + 3], f1.y);
        }
    }

#pragma unroll
    for (int f = 0; f < HID; ++f) {
        float s = sm[f], m = mx[f];
        for (int off = 32; off > 0; off >>= 1) {
            s += __shfl_down(s, off);
            m = fmaxf(m, __shfl_down(m, off));
        }
        sm[f] = s; mx[f] = m;
    }

    __shared__ float psum[4][HID], pmax[4][HID];
    int wave = threadIdx.x >> 6;
    int lane = threadIdx.x & 63;
    if (lane == 0) {
#pragma unroll
        for (int f = 0; f < HID; ++f) { psum[wave][f] = sm[f]; pmax[wave][f] = mx[f]; }
    }
    __syncthreads();

    __shared__ float fsum[HID], fmax_[HID];
    if (threadIdx.x < HID) {
        int f = threadIdx.x;
        fsum[f] = psum[0][f] + psum[1][f] + psum[2][f] + psum[3][f];
        fmax_[f] = fmaxf(fmaxf(pmax[0][f], pmax[1][f]), fmaxf(pmax[2][f], pmax[3][f]));
    }
    __syncthreads();

    if (threadIdx.x < NC) {
        int c = threadIdx.x;
        float cnt = (float)(hi - lo);
        float inv = 1.f / fmaxf(cnt, 1.f);
        float o = blin[c];
#pragma unroll
        for (int f = 0; f < HID; ++f) {
            o += fmax_[f] * Wlin[f * NC + c];
            o += (fsum[f] * inv) * Wlin[(HID + f) * NC + c];
        }
        out[g * NC + c] = o;
    }
}

// ================= fp32 fallback path (ws too small) =================
__global__ __launch_bounds__(256) void k_in_gemm(const float* __restrict__ x,
                                                 const float* __restrict__ W,
                                                 float* __restrict__ t) {
    __shared__ float sW[FIN * HID];
    for (int i = threadIdx.x; i < FIN * HID; i += blockDim.x) sW[i] = W[i];
    __syncthreads();
    int node = blockIdx.x * blockDim.x + threadIdx.x;
    if (node >= NN) return;
    float acc[HID];
#pragma unroll
    for (int f = 0; f < HID; ++f) acc[f] = 0.f;
    const float4* xr = (const float4*)(x + node * FIN);
    for (int q = 0; q < FIN / 4; ++q) {
        float4 xv = xr[q];
        int k = q * 4;
#pragma unroll
        for (int f = 0; f < HID; ++f)
            acc[f] += xv.x * sW[k * HID + f] + xv.y * sW[(k + 1) * HID + f] +
                      xv.z * sW[(k + 2) * HID + f] + xv.w * sW[(k + 3) * HID + f];
    }
    float4* tr = (float4*)(t + node * HID);
#pragma unroll
    for (int q = 0; q < HID / 4; ++q) {
        float4 v;
        v.x = acc[q * 4 + 0]; v.y = acc[q * 4 + 1];
        v.z = acc[q * 4 + 2]; v.w = acc[q * 4 + 3];
        tr[q] = v;
    }
}

__global__ __launch_bounds__(256) void k_scatter(const int* __restrict__ src,
                                                 const int* __restrict__ dst,
                                                 const float* __restrict__ w,
                                                 const float* __restrict__ t,
                                                 float* __restrict__ agg) {
    int e = blockIdx.x * blockDim.x + threadIdx.x;
    if (e >= NE) return;
    int s = src[e];
    int d = dst[e];
    float wt = w[e];
    const float4* tr = (const float4*)(t + (long)s * HID);
    float* ar = agg + (long)d * HID;
#pragma unroll
    for (int q = 0; q < HID / 4; ++q) {
        float4 v = tr[q];
        atomicAdd(ar + q * 4 + 0, v.x * wt);
        atomicAdd(ar + q * 4 + 1, v.y * wt);
        atomicAdd(ar + q * 4 + 2, v.z * wt);
        atomicAdd(ar + q * 4 + 3, v.w * wt);
    }
}

template <bool LAST>
__global__ __launch_bounds__(256) void k_node(const float* agg,
                                              const float* __restrict__ ba,
                                              const float* __restrict__ Wb,
                                              const float* __restrict__ bb,
                                              const float* __restrict__ Wnext,
                                              float* out) {
    __shared__ float sWb[HID * HID];
    __shared__ float sWn[HID * HID];
    __shared__ float sba[HID], sbb[HID];
    for (int i = threadIdx.x; i < HID * HID; i += blockDim.x) {
        sWb[i] = Wb[i];
        if (!LAST) sWn[i] = Wnext[i];
    }
    if (threadIdx.x < HID) {
        sba[threadIdx.x] = ba[threadIdx.x];
        sbb[threadIdx.x] = bb[threadIdx.x];
    }
    __syncthreads();
    int node = blockIdx.x * blockDim.x + threadIdx.x;
    if (node >= NN) return;

    float z1[HID];
    const float4* ar = (const float4*)(agg + (long)node * HID);
#pragma unroll
    for (int q = 0; q < HID / 4; ++q) {
        float4 v = ar[q];
        z1[q * 4 + 0] = v.x; z1[q * 4 + 1] = v.y;
        z1[q * 4 + 2] = v.z; z1[q * 4 + 3] = v.w;
    }
#pragma unroll
    for (int f = 0; f < HID; ++f) z1[f] = fmaxf(z1[f] + sba[f], 0.f);

    float z2[HID];
#pragma unroll
    for (int fo = 0; fo < HID; ++fo) {
        float a = sbb[fo];
#pragma unroll
        for (int k = 0; k < HID; ++k) a += z1[k] * sWb[k * HID + fo];
        z2[fo] = fmaxf(a, 0.f);
    }
    float ss = 0.f;
#pragma unroll
    for (int f = 0; f < HID; ++f) ss += z2[f] * z2[f];
    float scale = 1.f / fmaxf(sqrtf(ss), 1e-12f);
#pragma unroll
    for (int f = 0; f < HID; ++f) z2[f] *= scale;

    float res[HID];
    if (LAST) {
#pragma unroll
        for (int f = 0; f < HID; ++f) res[f] = z2[f];
    } else {
#pragma unroll
        for (int fo = 0; fo < HID; ++fo) {
            float a = 0.f;
#pragma unroll
            for (int k = 0; k < HID; ++k) a += z2[k] * sWn[k * HID + fo];
            res[fo] = a;
        }
    }
    float4* orow = (float4*)(out + (long)node * HID);
#pragma unroll
    for (int q = 0; q < HID / 4; ++q) {
        float4 v;
        v.x = res[q * 4 + 0]; v.y = res[q * 4 + 1];
        v.z = res[q * 4 + 2]; v.w = res[q * 4 + 3];
        orow[q] = v;
    }
}

__global__ __launch_bounds__(256) void k_pool(const float* __restrict__ h,
                                              const int* __restrict__ batch,
                                              const float* __restrict__ Wlin,
                                              const float* __restrict__ blin,
                                              float* __restrict__ out) {
    int g = blockIdx.x;
    __shared__ int s_lo, s_hi;
    if (threadIdx.x == 0) {
        int a = 0, b = NN;
        while (a < b) { int m = (a + b) >> 1; if (batch[m] < g) a = m + 1; else b = m; }
        s_lo = a;
        b = NN;
        while (a < b) { int m = (a + b) >> 1; if (batch[m] < g + 1) a = m + 1; else b = m; }
        s_hi = a;
    }
    __syncthreads();
    int lo = s_lo, hi = s_hi;
    float sm[HID], mx[HID];
#pragma unroll
    for (int f = 0; f < HID; ++f) { sm[f] = 0.f; mx[f] = 0.f; }
    for (int i = lo + threadIdx.x; i < hi; i += blockDim.x) {
        const float4* hr = (const float4*)(h + (long)i * HID);
#pragma unroll
        for (int q = 0; q < HID / 4; ++q) {
            float4 v = hr[q];
            sm[q * 4 + 0] += v.x; mx[q * 4 + 0] = fmaxf(mx[q * 4 + 0], v.x);
            sm[q * 4 + 1] += v.y; mx[q * 4 + 1] = fmaxf(mx[q * 4 + 1], v.y);
            sm[q * 4 + 2] += v.z; mx[q * 4 + 2] = fmaxf(mx[q * 4 + 2], v.z);
            sm[q * 4 + 3] += v.w; mx[q * 4 + 3] = fmaxf(mx[q * 4 + 3], v.w);
        }
    }
#pragma unroll
    for (int f = 0; f < HID; ++f) {
        float s = sm[f], m = mx[f];
        for (int off = 32; off > 0; off >>= 1) {
            s += __shfl_down(s, off);
            m = fmaxf(m, __shfl_down(m, off));
        }
        sm[f] = s; mx[f] = m;
    }
    __shared__ float psum[4][HID], pmax[4][HID];
    int wave = threadIdx.x >> 6;
    int lane = threadIdx.x & 63;
    if (lane == 0) {
#pragma unroll
        for (int f = 0; f < HID; ++f) { psum[wave][f] = sm[f]; pmax[wave][f] = mx[f]; }
    }
    __syncthreads();
    __shared__ float fsum[HID], fmax_[HID];
    if (threadIdx.x < HID) {
        int f = threadIdx.x;
        fsum[f] = psum[0][f] + psum[1][f] + psum[2][f] + psum[3][f];
        fmax_[f] = fmaxf(fmaxf(pmax[0][f], pmax[1][f]), fmaxf(pmax[2][f], pmax[3][f]));
    }
    __syncthreads();
    if (threadIdx.x < NC) {
        int c = threadIdx.x;
        float cnt = (float)(hi - lo);
        float inv = 1.f / fmaxf(cnt, 1.f);
        float o = blin[c];
#pragma unroll
        for (int f = 0; f < HID; ++f) {
            o += fmax_[f] * Wlin[f * NC + c];
            o += (fsum[f] * inv) * Wlin[(HID + f) * NC + c];
        }
        out[g * NC + c] = o;
    }
}

extern "C" void kernel_launch(void* const* d_in, const int* in_sizes, int n_in,
                              void* d_out, int out_size, void* d_ws, size_t ws_size,
                              hipStream_t stream) {
    const float* x   = (const float*)d_in[0];
    const int*   ei  = (const int*)d_in[1];
    const int*   bat = (const int*)d_in[2];
    const float* ew  = (const float*)d_in[3];
    const float* W1a = (const float*)d_in[4];
    const float* b1a = (const float*)d_in[5];
    const float* W1b = (const float*)d_in[6];
    const float* b1b = (const float*)d_in[7];
    const float* W2a = (const float*)d_in[8];
    const float* b2a = (const float*)d_in[9];
    const float* W2b = (const float*)d_in[10];
    const float* b2b = (const float*)d_in[11];
    const float* W3a = (const float*)d_in[12];
    const float* b3a = (const float*)d_in[13];
    const float* W3b = (const float*)d_in[14];
    const float* b3b = (const float*)d_in[15];
    const float* Wlin = (const float*)d_in[16];
    const float* blin = (const float*)d_in[17];

    const int* src = ei;
    const int* dst = ei + NE;

    dim3 gN((NN + 255) / 256);
    dim3 gQ8(((size_t)NN * 8 + 255) / 256);   // 8 lanes per node

    size_t szT    = (size_t)NN * HID * sizeof(float);         // 8 MB (fallback)
    size_t szCsr  = (size_t)NE * sizeof(int2);                // 25.6 MB
    size_t szOff  = ((size_t)(NN + 1) * sizeof(int) + 15) & ~(size_t)15;
    size_t szGh   = (size_t)NB1 * NBLK1 * sizeof(int);        // 400 KB
    size_t szGb   = (size_t)NBLK1 * NB1P * sizeof(int);       // 401 KB
    size_t szSm   = 4096;
    size_t szTh   = (size_t)NN * HID * sizeof(__half);        // 4 MB
    size_t szPart = szCsr > 2 * szTh ? szCsr : 2 * szTh;      // part ∪ (T0h,T1h)
    size_t need_radix = szCsr + szOff + szGh + szGb + 2 * szSm + szPart;

    if (ws_size >= need_radix) {
        char* p = (char*)d_ws;
        int2* csr    = (int2*)p;  p += szCsr;
        int*  offv   = (int*)p;   p += szOff;
        int*  ghist  = (int*)p;   p += szGh;
        int*  gbase  = (int*)p;   p += szGb;
        int*  bsum   = (int*)p;   p += szSm;
        int*  bstart = (int*)p;   p += szSm;
        int2* part   = (int2*)p;             // dead after k_p2; then hosts T0h,T1h
        __half* T0h = (__half*)part;
        __half* T1h = T0h + (size_t)NN * HID;

        // ---- build CSR (two-level counting sort, once; reused by 3 layers) ----
        k_p1count<<<NBLK1, BLK1T, 0, stream>>>(dst, ghist);
        k_breduceB<<<NB1, 256, 0, stream>>>(ghist, bsum);
        k_bscanB<<<1, 256, 0, stream>>>(bsum, bstart);
        k_bbase<<<NB1, 256, 0, stream>>>(ghist, bstart, gbase);
        k_p1scatter<<<NBLK1, BLK1T, 0, stream>>>(src, dst, ew, gbase, part);
        k_p2<<<NB1, 1024, 0, stream>>>(part, bstart, csr, offv);

        // ---- fused layers (f16 message tables, L2-resident) ----
        k_in_gemm_h<<<gN, 256, 0, stream>>>(x, W1a, T0h);
        k_layer<false><<<gQ8, 256, 0, stream>>>(offv, csr, T0h, b1a, W1b, b1b, W2a, T1h);
        k_layer<false><<<gQ8, 256, 0, stream>>>(offv, csr, T1h, b2a, W2b, b2b, W3a, T0h);
        k_layer<true><<<gQ8, 256, 0, stream>>>(offv, csr, T0h, b3a, W3b, b3b, nullptr, T1h);

        k_pool_h<<<NG, 256, 0, stream>>>(T1h, bat, Wlin, blin, (float*)d_out);
    } else {
        // fallback: fp32 atomic scatter path
        char* p = (char*)d_ws;
        float* T0 = (float*)p;  p += szT;
        float* T1 = (float*)p;
        dim3 gE((NE + 255) / 256);

        k_in_gemm<<<gN, 256, 0, stream>>>(x, W1a, T0);
        (void)hipMemsetAsync(T1, 0, szT, stream);
        k_scatter<<<gE, 256, 0, stream>>>(src, dst, ew, T0, T1);
        k_node<false><<<gN, 256, 0, stream>>>(T1, b1a, W1b, b1b, W2a, T0);
        (void)hipMemsetAsync(T1, 0, szT, stream);
        k_scatter<<<gE, 256, 0, stream>>>(src, dst, ew, T0, T1);
        k_node<false><<<gN, 256, 0, stream>>>(T1, b2a, W2b, b2b, W3a, T0);
        (void)hipMemsetAsync(T1, 0, szT, stream);
        k_scatter<<<gE, 256, 0, stream>>>(src, dst, ew, T0, T1);
        k_node<true><<<gN, 256, 0, stream>>>(T1, b3a, W3b, b3b, nullptr, T0);
        k_pool<<<NG, 256, 0, stream>>>(T0, bat, Wlin, blin, (float*)d_out);
    }
}